// Round 4
// baseline (165.884 us; speedup 1.0000x reference)
//
#include <hip/hip_runtime.h>

// YOLO loss: N=4096, S=14, B=2, NC=20. ncells = 802816 = 3136 blocks * 256.
// R4: coalesced LDS staging with occupancy-friendly shape (30.7 KB slab ->
// 5 blocks/CU, 20 waves/CU), ALL global loads (stage/mask/tbox/tcls) issued
// before the barrier, fused last-block finalize over 64 atomic slots.

#define GS 14
#define NCLS 20
#define BLOCK 256
#define CPB 256                    // cells per block, 1 per thread
#define SLAB_F4 (CPB * 30 / 4)     // 1920 float4 = 30720 B LDS
#define TAIL_F4 (SLAB_F4 - 7 * BLOCK)  // 128

// ws layout:
//   ((int*)ws)[0]          : mask format (0=int32, 1=uint8, 2=float32)
//   ((int*)ws)[8]          : block arrival counter
//   ws[64 + s*16 + k]      : atomic partial slots, s in [0,64), k in [0,4)

__global__ void yolo_init_kernel(const unsigned char* __restrict__ mask_bytes,
                                 int ncells, float* __restrict__ ws) {
    __shared__ int s_nz_off, s_gt1;
    if (threadIdx.x == 0) { s_nz_off = 0; s_gt1 = 0; }
    __syncthreads();
    int nscan = 4096;
    if (ncells < nscan) nscan = ncells;
    for (int i = threadIdx.x; i < nscan; i += blockDim.x) {
        unsigned char v = mask_bytes[i];
        if (v > 1) s_gt1 = 1;
        if ((i & 3) != 0 && v != 0) s_nz_off = 1;
    }
    __syncthreads();
    for (int i = threadIdx.x; i < 64 * 16; i += blockDim.x) ws[64 + i] = 0.0f;
    if (threadIdx.x == 0) {
        ((int*)ws)[0] = s_gt1 ? 2 : (s_nz_off ? 1 : 0);
        ((int*)ws)[8] = 0;
    }
}

__launch_bounds__(BLOCK)
__global__ void yolo_loss_kernel(const float* __restrict__ pred,
                                 const float* __restrict__ tbox,
                                 const float* __restrict__ tcls,
                                 const void* __restrict__ mask,
                                 float* __restrict__ ws,
                                 int ncells, float inv_n,
                                 float* __restrict__ out) {
    __shared__ float4 slab4[SLAB_F4];   // 30720 B
    __shared__ float sred[4][4];
    __shared__ float s_fin[4];
    __shared__ int s_last;

    const int fmt = ((const int*)ws)[0];
    const int tid = threadIdx.x;
    const int base = blockIdx.x * CPB;
    const float invS = 1.0f / (float)GS;

    float reg = 0.0f, cont = 0.0f, noobj = 0.0f, cls = 0.0f;

    if (base + CPB <= ncells) {
        const int cell = base + tid;

        // ---- issue phase: every global load goes out before the barrier ----
        const float4* src = reinterpret_cast<const float4*>(pred) +
                            (size_t)blockIdx.x * SLAB_F4;
        float4 st[8];
        #pragma unroll
        for (int i = 0; i < 7; ++i) st[i] = src[i * BLOCK + tid];
        if (tid < TAIL_F4) st[7] = src[7 * BLOCK + tid];

        bool m;
        if (fmt == 2)      m = ((const float*)mask)[cell] != 0.0f;
        else if (fmt == 1) m = ((const unsigned char*)mask)[cell] != 0;
        else               m = ((const int*)mask)[cell] != 0;

        const float4 tb4 = reinterpret_cast<const float4*>(tbox)[cell];

        float4 tc[5];
        tc[0] = tc[1] = tc[2] = tc[3] = tc[4] = make_float4(0.f, 0.f, 0.f, 0.f);
        if (m) {
            const float4* tp = reinterpret_cast<const float4*>(tcls) + (size_t)cell * 5;
            #pragma unroll
            for (int j = 0; j < 5; ++j) tc[j] = tp[j];
        }

        // ---- stage to LDS ----
        #pragma unroll
        for (int i = 0; i < 7; ++i) slab4[i * BLOCK + tid] = st[i];
        if (tid < TAIL_F4) slab4[7 * BLOCK + tid] = st[7];
        __syncthreads();

        // ---- compute: pure LDS + VALU ----
        const float* lv = reinterpret_cast<const float*>(slab4) + tid * 30;
        if (m) {
            const float tx = tb4.x, ty = tb4.y, tw = tb4.z, th = tb4.w;
            const float tcx = tx * invS, tcy = ty * invS;
            const float t_x1 = tcx - 0.5f * tw, t_y1 = tcy - 0.5f * th;
            const float t_x2 = tcx + 0.5f * tw, t_y2 = tcy + 0.5f * th;
            const float ta = (t_x2 - t_x1) * (t_y2 - t_y1);

            const float b0x = lv[0], b0y = lv[1], b0w = lv[2], b0h = lv[3], b0c = lv[4];
            const float b1x = lv[5], b1y = lv[6], b1w = lv[7], b1h = lv[8], b1c = lv[9];

            float iou0, iou1;
            {
                const float cx = b0x * invS, cy = b0y * invS;
                const float x1 = cx - 0.5f * b0w, y1 = cy - 0.5f * b0h;
                const float x2 = cx + 0.5f * b0w, y2 = cy + 0.5f * b0h;
                const float iw = fmaxf(fminf(x2, t_x2) - fmaxf(x1, t_x1), 0.0f);
                const float ih = fmaxf(fminf(y2, t_y2) - fmaxf(y1, t_y1), 0.0f);
                const float inter = iw * ih;
                const float pa = (x2 - x1) * (y2 - y1);
                iou0 = inter / (pa + ta - inter);
            }
            {
                const float cx = b1x * invS, cy = b1y * invS;
                const float x1 = cx - 0.5f * b1w, y1 = cy - 0.5f * b1h;
                const float x2 = cx + 0.5f * b1w, y2 = cy + 0.5f * b1h;
                const float iw = fmaxf(fminf(x2, t_x2) - fmaxf(x1, t_x1), 0.0f);
                const float ih = fmaxf(fminf(y2, t_y2) - fmaxf(y1, t_y1), 0.0f);
                const float inter = iw * ih;
                const float pa = (x2 - x1) * (y2 - y1);
                iou1 = inter / (pa + ta - inter);
            }

            const bool sel1 = iou1 > iou0;   // jnp.argmax: first max wins -> strict >
            const float biou = fmaxf(iou0, iou1);
            const float rx = sel1 ? b1x : b0x;
            const float ry = sel1 ? b1y : b0y;
            const float rw = sel1 ? b1w : b0w;
            const float rh = sel1 ? b1h : b0h;
            const float rc = sel1 ? b1c : b0c;

            const float d0 = rx - tx, d1 = ry - ty;
            const float d2 = sqrtf(rw) - sqrtf(tw);
            const float d3 = sqrtf(rh) - sqrtf(th);
            reg += d0 * d0 + d1 * d1 + d2 * d2 + d3 * d3;

            const float dc = rc - biou;
            cont += dc * dc;

            float csum = 0.0f;
            #pragma unroll
            for (int j = 0; j < 5; ++j) {
                float d;
                d = lv[10 + j * 4 + 0] - tc[j].x; csum += d * d;
                d = lv[10 + j * 4 + 1] - tc[j].y; csum += d * d;
                d = lv[10 + j * 4 + 2] - tc[j].z; csum += d * d;
                d = lv[10 + j * 4 + 3] - tc[j].w; csum += d * d;
            }
            cls += csum;
        } else {
            const float c0 = lv[4], c1 = lv[9];
            noobj += c0 * c0 + c1 * c1;
        }
    } else {
        // generic tail (not hit for ncells = 802816); block-uniform branch
        for (int cell = base + tid; cell < ncells; cell += BLOCK) {
            bool m;
            if (fmt == 2)      m = ((const float*)mask)[cell] != 0.0f;
            else if (fmt == 1) m = ((const unsigned char*)mask)[cell] != 0;
            else               m = ((const int*)mask)[cell] != 0;
            const float* p = pred + (size_t)cell * 30;
            if (m) {
                const float tx = tbox[(size_t)cell * 4 + 0], ty = tbox[(size_t)cell * 4 + 1];
                const float tw = tbox[(size_t)cell * 4 + 2], th = tbox[(size_t)cell * 4 + 3];
                const float tcx = tx * invS, tcy = ty * invS;
                const float t_x1 = tcx - 0.5f * tw, t_y1 = tcy - 0.5f * th;
                const float t_x2 = tcx + 0.5f * tw, t_y2 = tcy + 0.5f * th;
                const float ta = (t_x2 - t_x1) * (t_y2 - t_y1);
                float iou[2];
                #pragma unroll
                for (int b = 0; b < 2; ++b) {
                    const float cx = p[b * 5 + 0] * invS, cy = p[b * 5 + 1] * invS;
                    const float w = p[b * 5 + 2], h = p[b * 5 + 3];
                    const float x1 = cx - 0.5f * w, y1 = cy - 0.5f * h;
                    const float x2 = cx + 0.5f * w, y2 = cy + 0.5f * h;
                    const float iw = fmaxf(fminf(x2, t_x2) - fmaxf(x1, t_x1), 0.0f);
                    const float ih = fmaxf(fminf(y2, t_y2) - fmaxf(y1, t_y1), 0.0f);
                    const float inter = iw * ih;
                    const float pa = (x2 - x1) * (y2 - y1);
                    iou[b] = inter / (pa + ta - inter);
                }
                const bool sel1 = iou[1] > iou[0];
                const float biou = fmaxf(iou[0], iou[1]);
                const int o = sel1 ? 5 : 0;
                const float d0 = p[o + 0] - tx, d1 = p[o + 1] - ty;
                const float d2 = sqrtf(p[o + 2]) - sqrtf(tw);
                const float d3 = sqrtf(p[o + 3]) - sqrtf(th);
                reg += d0 * d0 + d1 * d1 + d2 * d2 + d3 * d3;
                const float dc = p[o + 4] - biou;
                cont += dc * dc;
                for (int c = 0; c < NCLS; ++c) {
                    const float d = p[10 + c] - tcls[(size_t)cell * NCLS + c];
                    cls += d * d;
                }
            } else {
                noobj += p[4] * p[4] + p[9] * p[9];
            }
        }
        __syncthreads();   // match main path's barrier count
    }

    // ---- block reduce ----
    #pragma unroll
    for (int off = 32; off > 0; off >>= 1) {
        reg   += __shfl_down(reg, off);
        cont  += __shfl_down(cont, off);
        noobj += __shfl_down(noobj, off);
        cls   += __shfl_down(cls, off);
    }
    const int wave = tid >> 6;
    if ((tid & 63) == 0) {
        sred[wave][0] = reg; sred[wave][1] = cont;
        sred[wave][2] = noobj; sred[wave][3] = cls;
    }
    __syncthreads();

    if (tid == 0) {
        float r = 0, c = 0, no = 0, cl = 0;
        #pragma unroll
        for (int w = 0; w < 4; ++w) {
            r += sred[w][0]; c += sred[w][1]; no += sred[w][2]; cl += sred[w][3];
        }
        float* slot = ws + 64 + (size_t)(blockIdx.x & 63) * 16;
        atomicAdd(&slot[0], r);
        atomicAdd(&slot[1], c);
        atomicAdd(&slot[2], no);
        atomicAdd(&slot[3], cl);
        __threadfence();
        const int prev = atomicAdd((int*)ws + 8, 1);
        s_last = (prev == (int)gridDim.x - 1);
    }
    __syncthreads();

    // ---- last block folds the 64 slots and writes the output ----
    if (s_last) {
        __threadfence();
        const int w = tid >> 6, l = tid & 63;   // wave w sums counter w over 64 slots
        float v = __hip_atomic_load(ws + 64 + (size_t)l * 16 + w,
                                    __ATOMIC_RELAXED, __HIP_MEMORY_SCOPE_AGENT);
        #pragma unroll
        for (int off = 32; off > 0; off >>= 1) v += __shfl_down(v, off);
        if (l == 0) s_fin[w] = v;
        __syncthreads();
        if (tid == 0) {
            const float R = s_fin[0], C = s_fin[1], NO = s_fin[2], CL = s_fin[3];
            out[0] = (5.0f * R + 0.5f * NO + C + CL) * inv_n;
            out[1] = R;
            out[2] = C;
            out[3] = NO;
            out[4] = CL;
        }
    }
}

extern "C" void kernel_launch(void* const* d_in, const int* in_sizes, int n_in,
                              void* d_out, int out_size, void* d_ws, size_t ws_size,
                              hipStream_t stream) {
    const float* pred = (const float*)d_in[0];
    const float* tbox = (const float*)d_in[1];
    const float* tcls = (const float*)d_in[2];
    const void*  mask = d_in[3];
    float* ws  = (float*)d_ws;
    float* out = (float*)d_out;

    const int ncells = in_sizes[3];                 // N * S * S
    const int n_img  = ncells / (GS * GS);          // N
    const float inv_n = 1.0f / (float)n_img;

    yolo_init_kernel<<<1, 256, 0, stream>>>((const unsigned char*)mask, ncells, ws);

    const int grid = (ncells + CPB - 1) / CPB;      // 3136
    yolo_loss_kernel<<<grid, BLOCK, 0, stream>>>(pred, tbox, tcls, mask, ws,
                                                 ncells, inv_n, out);
}

// Round 5
// 113.433 us; speedup vs baseline: 1.4624x; 1.4624x over previous
//
#include <hip/hip_runtime.h>

// YOLO loss: N=4096, S=14, B=2, NC=20. ncells = 802816 = 3136 blocks * 256.
// R5: coalesced staging via __builtin_amdgcn_global_load_lds (width 16,
// zero VGPR cost -- fixes R4's scratch-spill disaster), 30.7 KB slab
// (5 blocks/CU), fused last-block finalize.

#define GS 14
#define NCLS 20
#define BLOCK 256
#define CPB 256                    // cells per block, 1 per thread
#define SLAB_F4 (CPB * 30 / 4)     // 1920 float4 = 30720 B LDS
#define FULL_IT 7                  // 7*256 = 1792 float4
#define TAIL_F4 (SLAB_F4 - FULL_IT * BLOCK)  // 128 (= 2 waves)

// ws layout:
//   ((int*)ws)[0]          : mask format (0=int32, 1=uint8, 2=float32)
//   ((int*)ws)[8]          : block arrival counter
//   ws[64 + s*16 + k]      : atomic partial slots, s in [0,64), k in [0,4)

__global__ void yolo_init_kernel(const unsigned char* __restrict__ mask_bytes,
                                 int ncells, float* __restrict__ ws) {
    __shared__ int s_nz_off, s_gt1;
    if (threadIdx.x == 0) { s_nz_off = 0; s_gt1 = 0; }
    __syncthreads();
    int nscan = 4096;
    if (ncells < nscan) nscan = ncells;
    for (int i = threadIdx.x; i < nscan; i += blockDim.x) {
        unsigned char v = mask_bytes[i];
        if (v > 1) s_gt1 = 1;
        if ((i & 3) != 0 && v != 0) s_nz_off = 1;
    }
    __syncthreads();
    for (int i = threadIdx.x; i < 64 * 16; i += blockDim.x) ws[64 + i] = 0.0f;
    if (threadIdx.x == 0) {
        ((int*)ws)[0] = s_gt1 ? 2 : (s_nz_off ? 1 : 0);
        ((int*)ws)[8] = 0;
    }
}

// async global->LDS, 16 bytes per lane. LDS dest must be wave-uniform base
// (HW adds lane*16); global src is per-lane.
__device__ __forceinline__ void gload_lds16(const float4* g, float4* l) {
    __builtin_amdgcn_global_load_lds(
        (const __attribute__((address_space(1))) void*)g,
        (__attribute__((address_space(3))) void*)l, 16, 0, 0);
}

__launch_bounds__(BLOCK)
__global__ void yolo_loss_kernel(const float* __restrict__ pred,
                                 const float* __restrict__ tbox,
                                 const float* __restrict__ tcls,
                                 const void* __restrict__ mask,
                                 float* __restrict__ ws,
                                 int ncells, float inv_n,
                                 float* __restrict__ out) {
    __shared__ float4 slab4[SLAB_F4];   // 30720 B
    __shared__ float sred[4][4];
    __shared__ float s_fin[4];
    __shared__ int s_last;

    const int fmt = ((const int*)ws)[0];
    const int tid = threadIdx.x;
    const int wv = tid >> 6;
    const int base = blockIdx.x * CPB;
    const float invS = 1.0f / (float)GS;

    float reg = 0.0f, cont = 0.0f, noobj = 0.0f, cls = 0.0f;

    if (base + CPB <= ncells) {
        const int cell = base + tid;

        // ---- staging: DMA pred slab to LDS, no VGPRs consumed ----
        const float4* src = reinterpret_cast<const float4*>(pred) +
                            (size_t)blockIdx.x * SLAB_F4;
        #pragma unroll
        for (int i = 0; i < FULL_IT; ++i)
            gload_lds16(src + i * BLOCK + tid, slab4 + i * BLOCK + wv * 64);
        if (wv < 2)   // tail: 128 float4, waves 0-1 (wave-uniform cond)
            gload_lds16(src + FULL_IT * BLOCK + tid,
                        slab4 + FULL_IT * BLOCK + wv * 64);

        // ---- independent small loads, issued while DMA is in flight ----
        bool m;
        if (fmt == 2)      m = ((const float*)mask)[cell] != 0.0f;
        else if (fmt == 1) m = ((const unsigned char*)mask)[cell] != 0;
        else               m = ((const int*)mask)[cell] != 0;

        float4 tb4 = make_float4(0.f, 0.f, 0.f, 0.f);
        if (m) tb4 = reinterpret_cast<const float4*>(tbox)[cell];

        __syncthreads();   // drains vmcnt (global_load_lds) + lgkm

        // ---- compute: LDS + VALU, tcls loaded on demand ----
        const float* lv = reinterpret_cast<const float*>(slab4) + tid * 30;
        if (m) {
            const float tx = tb4.x, ty = tb4.y, tw = tb4.z, th = tb4.w;
            const float tcx = tx * invS, tcy = ty * invS;
            const float t_x1 = tcx - 0.5f * tw, t_y1 = tcy - 0.5f * th;
            const float t_x2 = tcx + 0.5f * tw, t_y2 = tcy + 0.5f * th;
            const float ta = (t_x2 - t_x1) * (t_y2 - t_y1);

            const float b0x = lv[0], b0y = lv[1], b0w = lv[2], b0h = lv[3], b0c = lv[4];
            const float b1x = lv[5], b1y = lv[6], b1w = lv[7], b1h = lv[8], b1c = lv[9];

            float iou0, iou1;
            {
                const float cx = b0x * invS, cy = b0y * invS;
                const float x1 = cx - 0.5f * b0w, y1 = cy - 0.5f * b0h;
                const float x2 = cx + 0.5f * b0w, y2 = cy + 0.5f * b0h;
                const float iw = fmaxf(fminf(x2, t_x2) - fmaxf(x1, t_x1), 0.0f);
                const float ih = fmaxf(fminf(y2, t_y2) - fmaxf(y1, t_y1), 0.0f);
                const float inter = iw * ih;
                const float pa = (x2 - x1) * (y2 - y1);
                iou0 = inter / (pa + ta - inter);
            }
            {
                const float cx = b1x * invS, cy = b1y * invS;
                const float x1 = cx - 0.5f * b1w, y1 = cy - 0.5f * b1h;
                const float x2 = cx + 0.5f * b1w, y2 = cy + 0.5f * b1h;
                const float iw = fmaxf(fminf(x2, t_x2) - fmaxf(x1, t_x1), 0.0f);
                const float ih = fmaxf(fminf(y2, t_y2) - fmaxf(y1, t_y1), 0.0f);
                const float inter = iw * ih;
                const float pa = (x2 - x1) * (y2 - y1);
                iou1 = inter / (pa + ta - inter);
            }

            const bool sel1 = iou1 > iou0;   // jnp.argmax: first max wins -> strict >
            const float biou = fmaxf(iou0, iou1);
            const float rx = sel1 ? b1x : b0x;
            const float ry = sel1 ? b1y : b0y;
            const float rw = sel1 ? b1w : b0w;
            const float rh = sel1 ? b1h : b0h;
            const float rc = sel1 ? b1c : b0c;

            const float d0 = rx - tx, d1 = ry - ty;
            const float d2 = sqrtf(rw) - sqrtf(tw);
            const float d3 = sqrtf(rh) - sqrtf(th);
            reg += d0 * d0 + d1 * d1 + d2 * d2 + d3 * d3;

            const float dc = rc - biou;
            cont += dc * dc;

            const float4* tp = reinterpret_cast<const float4*>(tcls) + (size_t)cell * 5;
            float csum = 0.0f;
            #pragma unroll
            for (int j = 0; j < 5; ++j) {
                const float4 t4 = tp[j];
                float d;
                d = lv[10 + j * 4 + 0] - t4.x; csum += d * d;
                d = lv[10 + j * 4 + 1] - t4.y; csum += d * d;
                d = lv[10 + j * 4 + 2] - t4.z; csum += d * d;
                d = lv[10 + j * 4 + 3] - t4.w; csum += d * d;
            }
            cls += csum;
        } else {
            const float c0 = lv[4], c1 = lv[9];
            noobj += c0 * c0 + c1 * c1;
        }
    } else {
        // generic tail path (not hit for ncells = 802816)
        for (int cell = base + tid; cell < ncells; cell += BLOCK) {
            bool m;
            if (fmt == 2)      m = ((const float*)mask)[cell] != 0.0f;
            else if (fmt == 1) m = ((const unsigned char*)mask)[cell] != 0;
            else               m = ((const int*)mask)[cell] != 0;
            const float* p = pred + (size_t)cell * 30;
            if (m) {
                const float tx = tbox[(size_t)cell * 4 + 0], ty = tbox[(size_t)cell * 4 + 1];
                const float tw = tbox[(size_t)cell * 4 + 2], th = tbox[(size_t)cell * 4 + 3];
                const float tcx = tx * invS, tcy = ty * invS;
                const float t_x1 = tcx - 0.5f * tw, t_y1 = tcy - 0.5f * th;
                const float t_x2 = tcx + 0.5f * tw, t_y2 = tcy + 0.5f * th;
                const float ta = (t_x2 - t_x1) * (t_y2 - t_y1);
                float iou[2];
                #pragma unroll
                for (int b = 0; b < 2; ++b) {
                    const float cx = p[b * 5 + 0] * invS, cy = p[b * 5 + 1] * invS;
                    const float w = p[b * 5 + 2], h = p[b * 5 + 3];
                    const float x1 = cx - 0.5f * w, y1 = cy - 0.5f * h;
                    const float x2 = cx + 0.5f * w, y2 = cy + 0.5f * h;
                    const float iw = fmaxf(fminf(x2, t_x2) - fmaxf(x1, t_x1), 0.0f);
                    const float ih = fmaxf(fminf(y2, t_y2) - fmaxf(y1, t_y1), 0.0f);
                    const float inter = iw * ih;
                    const float pa = (x2 - x1) * (y2 - y1);
                    iou[b] = inter / (pa + ta - inter);
                }
                const bool sel1 = iou[1] > iou[0];
                const float biou = fmaxf(iou[0], iou[1]);
                const int o = sel1 ? 5 : 0;
                const float d0 = p[o + 0] - tx, d1 = p[o + 1] - ty;
                const float d2 = sqrtf(p[o + 2]) - sqrtf(tw);
                const float d3 = sqrtf(p[o + 3]) - sqrtf(th);
                reg += d0 * d0 + d1 * d1 + d2 * d2 + d3 * d3;
                const float dc = p[o + 4] - biou;
                cont += dc * dc;
                for (int c = 0; c < NCLS; ++c) {
                    const float d = p[10 + c] - tcls[(size_t)cell * NCLS + c];
                    cls += d * d;
                }
            } else {
                noobj += p[4] * p[4] + p[9] * p[9];
            }
        }
        __syncthreads();   // match main path's barrier count
    }

    // ---- block reduce ----
    #pragma unroll
    for (int off = 32; off > 0; off >>= 1) {
        reg   += __shfl_down(reg, off);
        cont  += __shfl_down(cont, off);
        noobj += __shfl_down(noobj, off);
        cls   += __shfl_down(cls, off);
    }
    if ((tid & 63) == 0) {
        sred[wv][0] = reg; sred[wv][1] = cont;
        sred[wv][2] = noobj; sred[wv][3] = cls;
    }
    __syncthreads();

    if (tid == 0) {
        float r = 0, c = 0, no = 0, cl = 0;
        #pragma unroll
        for (int w = 0; w < 4; ++w) {
            r += sred[w][0]; c += sred[w][1]; no += sred[w][2]; cl += sred[w][3];
        }
        float* slot = ws + 64 + (size_t)(blockIdx.x & 63) * 16;
        atomicAdd(&slot[0], r);
        atomicAdd(&slot[1], c);
        atomicAdd(&slot[2], no);
        atomicAdd(&slot[3], cl);
        __threadfence();
        const int prev = atomicAdd((int*)ws + 8, 1);
        s_last = (prev == (int)gridDim.x - 1);
    }
    __syncthreads();

    // ---- last block folds the 64 slots and writes the output ----
    if (s_last) {
        __threadfence();
        const int w = tid >> 6, l = tid & 63;   // wave w sums counter w over 64 slots
        float v = __hip_atomic_load(ws + 64 + (size_t)l * 16 + w,
                                    __ATOMIC_RELAXED, __HIP_MEMORY_SCOPE_AGENT);
        #pragma unroll
        for (int off = 32; off > 0; off >>= 1) v += __shfl_down(v, off);
        if (l == 0) s_fin[w] = v;
        __syncthreads();
        if (tid == 0) {
            const float R = s_fin[0], C = s_fin[1], NO = s_fin[2], CL = s_fin[3];
            out[0] = (5.0f * R + 0.5f * NO + C + CL) * inv_n;
            out[1] = R;
            out[2] = C;
            out[3] = NO;
            out[4] = CL;
        }
    }
}

extern "C" void kernel_launch(void* const* d_in, const int* in_sizes, int n_in,
                              void* d_out, int out_size, void* d_ws, size_t ws_size,
                              hipStream_t stream) {
    const float* pred = (const float*)d_in[0];
    const float* tbox = (const float*)d_in[1];
    const float* tcls = (const float*)d_in[2];
    const void*  mask = d_in[3];
    float* ws  = (float*)d_ws;
    float* out = (float*)d_out;

    const int ncells = in_sizes[3];                 // N * S * S
    const int n_img  = ncells / (GS * GS);          // N
    const float inv_n = 1.0f / (float)n_img;

    yolo_init_kernel<<<1, 256, 0, stream>>>((const unsigned char*)mask, ncells, ws);

    const int grid = (ncells + CPB - 1) / CPB;      // 3136
    yolo_loss_kernel<<<grid, BLOCK, 0, stream>>>(pred, tbox, tcls, mask, ws,
                                                 ncells, inv_n, out);
}

// Round 6
// 34.952 us; speedup vs baseline: 4.7460x; 3.2454x over previous
//
#include <hip/hip_runtime.h>

// YOLO loss: N=4096, S=14, B=2, NC=20. ncells = 802816 = 1568 blocks * 512.
// R6 = R2 (proven 49 us: direct 15x dwordx4 loads, 2 cells/thread, 64-slot
// spread atomics, tiny finalize) + per-block mask-dtype sniff (kills the
// serial init kernel) + unconditional tbox prefetch (kills a dependent
// round-trip for obj threads). Staging/barrier variants disproven (R3-R5).

#define GS 14
#define NCLS 20
#define BLOCK 256
#define CPT 2
#define CPB (BLOCK * CPT)   // 512 cells per block
#define NSLOTS 64
#define SLOT_STRIDE 16      // floats = 64 B

// ws layout (floats): slots at ws[s*16 + k], s in [0,64), k in [0,4)
// zeroed each call by hipMemsetAsync.

template <int CB>
__device__ __forceinline__ void cell_compute(const float (&v)[60],
                                             const float4 tb4,
                                             const float* __restrict__ tcls,
                                             int cell, bool m,
                                             float& reg, float& cont,
                                             float& noobj, float& cls) {
    const float invS = 1.0f / (float)GS;
    if (m) {
        const float tx = tb4.x, ty = tb4.y, tw = tb4.z, th = tb4.w;

        const float tcx = tx * invS, tcy = ty * invS;
        const float t_x1 = tcx - 0.5f * tw, t_y1 = tcy - 0.5f * th;
        const float t_x2 = tcx + 0.5f * tw, t_y2 = tcy + 0.5f * th;
        const float ta = (t_x2 - t_x1) * (t_y2 - t_y1);

        const float b0x = v[CB + 0], b0y = v[CB + 1], b0w = v[CB + 2], b0h = v[CB + 3], b0c = v[CB + 4];
        const float b1x = v[CB + 5], b1y = v[CB + 6], b1w = v[CB + 7], b1h = v[CB + 8], b1c = v[CB + 9];

        float iou0, iou1;
        {
            const float cx = b0x * invS, cy = b0y * invS;
            const float x1 = cx - 0.5f * b0w, y1 = cy - 0.5f * b0h;
            const float x2 = cx + 0.5f * b0w, y2 = cy + 0.5f * b0h;
            const float iw = fmaxf(fminf(x2, t_x2) - fmaxf(x1, t_x1), 0.0f);
            const float ih = fmaxf(fminf(y2, t_y2) - fmaxf(y1, t_y1), 0.0f);
            const float inter = iw * ih;
            const float pa = (x2 - x1) * (y2 - y1);
            iou0 = inter / (pa + ta - inter);
        }
        {
            const float cx = b1x * invS, cy = b1y * invS;
            const float x1 = cx - 0.5f * b1w, y1 = cy - 0.5f * b1h;
            const float x2 = cx + 0.5f * b1w, y2 = cy + 0.5f * b1h;
            const float iw = fmaxf(fminf(x2, t_x2) - fmaxf(x1, t_x1), 0.0f);
            const float ih = fmaxf(fminf(y2, t_y2) - fmaxf(y1, t_y1), 0.0f);
            const float inter = iw * ih;
            const float pa = (x2 - x1) * (y2 - y1);
            iou1 = inter / (pa + ta - inter);
        }

        const bool sel1 = iou1 > iou0;   // jnp.argmax: first max wins -> strict >
        const float biou = fmaxf(iou0, iou1);
        const float rx = sel1 ? b1x : b0x;
        const float ry = sel1 ? b1y : b0y;
        const float rw = sel1 ? b1w : b0w;
        const float rh = sel1 ? b1h : b0h;
        const float rc = sel1 ? b1c : b0c;

        const float d0 = rx - tx, d1 = ry - ty;
        const float d2 = sqrtf(rw) - sqrtf(tw);
        const float d3 = sqrtf(rh) - sqrtf(th);
        reg += d0 * d0 + d1 * d1 + d2 * d2 + d3 * d3;

        const float dc = rc - biou;
        cont += dc * dc;

        const float4* tc4 = reinterpret_cast<const float4*>(tcls + (size_t)cell * NCLS);
        float csum = 0.0f;
        #pragma unroll
        for (int j = 0; j < 5; ++j) {
            const float4 t4 = tc4[j];
            float d;
            d = v[CB + 10 + j * 4 + 0] - t4.x; csum += d * d;
            d = v[CB + 10 + j * 4 + 1] - t4.y; csum += d * d;
            d = v[CB + 10 + j * 4 + 2] - t4.z; csum += d * d;
            d = v[CB + 10 + j * 4 + 3] - t4.w; csum += d * d;
        }
        cls += csum;
    } else {
        const float c0 = v[CB + 4], c1 = v[CB + 9];
        noobj += c0 * c0 + c1 * c1;
    }
}

__launch_bounds__(BLOCK)
__global__ void yolo_loss_kernel(const float* __restrict__ pred,
                                 const float* __restrict__ tbox,
                                 const float* __restrict__ tcls,
                                 const void* __restrict__ mask,
                                 float* __restrict__ ws,
                                 int ncells) {
    const int tid = threadIdx.x;

    // ---- per-block mask-dtype sniff on the first 4KB (L2/L3-hot) ----
    //   fmt=0: int32 (nonzero bytes only at off%4==0, all <=1)
    //   fmt=1: uint8/bool (nonzero byte at off%4!=0, all <=1)
    //   fmt=2: float32 (some byte >1, e.g. 0x3f of 1.0f)
    int my_gt1 = 0, my_nzoff = 0;
    if (ncells >= 4096) {
        const uint4 w4 = reinterpret_cast<const uint4*>(mask)[tid];  // bytes 16t..16t+15
        const unsigned a = w4.x | w4.y | w4.z | w4.w;
        my_gt1   = (a & 0xFEFEFEFEu) != 0;   // any byte with a bit above bit0
        my_nzoff = (a & 0xFFFFFF00u) != 0;   // any nonzero byte at off%4 != 0
    } else if (tid == 0) {
        const unsigned char* mb = (const unsigned char*)mask;
        for (int i = 0; i < ncells; ++i) {
            if (mb[i] > 1) my_gt1 = 1;
            if ((i & 3) != 0 && mb[i] != 0) my_nzoff = 1;
        }
    }
    const int gt1   = __syncthreads_or(my_gt1);
    const int nzoff = __syncthreads_or(my_nzoff);
    const int fmt = gt1 ? 2 : (nzoff ? 1 : 0);

    const int g = blockIdx.x * BLOCK + tid;
    const int c0 = g * CPT;

    float reg = 0.0f, cont = 0.0f, noobj = 0.0f, cls = 0.0f;

    if (c0 + CPT <= ncells) {
        // 15 dwordx4: this thread's 240B (two cells), contiguous.
        float v[60];
        float4* v4 = reinterpret_cast<float4*>(v);
        const float4* prow = reinterpret_cast<const float4*>(pred) + (size_t)g * 15;
        #pragma unroll
        for (int j = 0; j < 15; ++j) v4[j] = prow[j];

        bool m0, m1;
        if (fmt == 2) {
            const float2 mm = reinterpret_cast<const float2*>(mask)[g];
            m0 = mm.x != 0.0f; m1 = mm.y != 0.0f;
        } else if (fmt == 1) {
            const uchar2 mm = reinterpret_cast<const uchar2*>(mask)[g];
            m0 = mm.x != 0; m1 = mm.y != 0;
        } else {
            const int2 mm = reinterpret_cast<const int2*>(mask)[g];
            m0 = mm.x != 0; m1 = mm.y != 0;
        }

        // unconditional tbox prefetch: independent of mask, issues with preds
        const float4 tb0 = reinterpret_cast<const float4*>(tbox)[c0];
        const float4 tb1 = reinterpret_cast<const float4*>(tbox)[c0 + 1];

        cell_compute<0>(v, tb0, tcls, c0,     m0, reg, cont, noobj, cls);
        cell_compute<30>(v, tb1, tcls, c0 + 1, m1, reg, cont, noobj, cls);
    } else if (c0 < ncells) {
        // scalar tail (not hit when ncells % 512 == 0)
        for (int cell = c0; cell < ncells; ++cell) {
            bool m;
            if (fmt == 2)      m = ((const float*)mask)[cell] != 0.0f;
            else if (fmt == 1) m = ((const unsigned char*)mask)[cell] != 0;
            else               m = ((const int*)mask)[cell] != 0;
            float v[60];
            #pragma unroll
            for (int f = 0; f < 30; ++f) v[f] = pred[(size_t)cell * 30 + f];
            float4 tb;
            tb.x = tbox[(size_t)cell * 4 + 0];
            tb.y = tbox[(size_t)cell * 4 + 1];
            tb.z = tbox[(size_t)cell * 4 + 2];
            tb.w = tbox[(size_t)cell * 4 + 3];
            cell_compute<0>(v, tb, tcls, cell, m, reg, cont, noobj, cls);
        }
    }

    // ---- wave64 reduce ----
    #pragma unroll
    for (int off = 32; off > 0; off >>= 1) {
        reg   += __shfl_down(reg, off);
        cont  += __shfl_down(cont, off);
        noobj += __shfl_down(noobj, off);
        cls   += __shfl_down(cls, off);
    }

    __shared__ float sred[4][4];  // [wave][counter]
    const int wave = tid >> 6;
    if ((tid & 63) == 0) {
        sred[wave][0] = reg; sred[wave][1] = cont;
        sred[wave][2] = noobj; sred[wave][3] = cls;
    }
    __syncthreads();
    if (tid == 0) {
        float r = 0, c = 0, no = 0, cl = 0;
        #pragma unroll
        for (int w = 0; w < 4; ++w) {
            r += sred[w][0]; c += sred[w][1]; no += sred[w][2]; cl += sred[w][3];
        }
        float* slot = ws + (size_t)(blockIdx.x & (NSLOTS - 1)) * SLOT_STRIDE;
        atomicAdd(&slot[0], r);
        atomicAdd(&slot[1], c);
        atomicAdd(&slot[2], no);
        atomicAdd(&slot[3], cl);
    }
}

__global__ void yolo_finalize_kernel(const float* __restrict__ ws,
                                     float* __restrict__ out, float inv_n) {
    // one wave: thread t owns slot t
    const int t = threadIdx.x;
    float reg   = ws[t * SLOT_STRIDE + 0];
    float cont  = ws[t * SLOT_STRIDE + 1];
    float noobj = ws[t * SLOT_STRIDE + 2];
    float cls   = ws[t * SLOT_STRIDE + 3];
    #pragma unroll
    for (int off = 32; off > 0; off >>= 1) {
        reg   += __shfl_down(reg, off);
        cont  += __shfl_down(cont, off);
        noobj += __shfl_down(noobj, off);
        cls   += __shfl_down(cls, off);
    }
    if (t == 0) {
        const float total = (5.0f * reg + 0.5f * noobj + cont + cls) * inv_n;
        out[0] = total;
        out[1] = reg;
        out[2] = cont;
        out[3] = noobj;
        out[4] = cls;
    }
}

extern "C" void kernel_launch(void* const* d_in, const int* in_sizes, int n_in,
                              void* d_out, int out_size, void* d_ws, size_t ws_size,
                              hipStream_t stream) {
    const float* pred = (const float*)d_in[0];
    const float* tbox = (const float*)d_in[1];
    const float* tcls = (const float*)d_in[2];
    const void*  mask = d_in[3];
    float* ws  = (float*)d_ws;
    float* out = (float*)d_out;

    const int ncells = in_sizes[3];                 // N * S * S
    const int n_img  = ncells / (GS * GS);          // N
    const float inv_n = 1.0f / (float)n_img;

    hipMemsetAsync(ws, 0, NSLOTS * SLOT_STRIDE * sizeof(float), stream);

    const int grid = (ncells + CPB - 1) / CPB;      // 1568
    yolo_loss_kernel<<<grid, BLOCK, 0, stream>>>(pred, tbox, tcls, mask, ws, ncells);

    yolo_finalize_kernel<<<1, 64, 0, stream>>>(ws, out, inv_n);
}